// Round 11
// baseline (371.601 us; speedup 1.0000x reference)
//
#include <hip/hip_runtime.h>
#include <hip/hip_bf16.h>

// Problem constants (NoiseEfficientNet): B=32, Cin=96, Cout=144, H=W=56, 3x3 pad1
#define B_    32
#define CIN   96
#define COUT  144
#define H_    56
#define W_    56
#define HW    3136      // 56*56
#define NPIX  100352    // 32*3136
#define KTOT  864       // 9 taps * 96 ci
#define MT    128       // conv tile: 4 waves x 32 px
#define TAPSZ (COUT*CIN) // 13824 shorts per tap in Wt
// padded input layout: [B][58][58][96] bf16, zero borders
#define W2    58
#define PLANE (W2*W2)   // 3364
#define XTP_SHORTS ((size_t)B_ * PLANE * CIN)  // 10,334,208

#define NBLK  768       // fused grid: 3 blocks/CU, co-resident (LDS cap = 5)
#define TB 1568
#define WB 486
#define EB 18
#define ZB 342
#define PREPB (TB + WB + EB + ZB)   // 2414 virtual prep blocks
#define CONVB (NPIX / MT)           // 784 conv tiles

typedef short  short8  __attribute__((ext_vector_type(8)));
typedef float  floatx4 __attribute__((ext_vector_type(4)));

__device__ __forceinline__ unsigned short f2bf(float f) {
    union { float f; unsigned int u; } v; v.f = f;
    unsigned int u = v.u;
    return (unsigned short)((u + 0x7FFFu + ((u >> 16) & 1u)) >> 16);  // RNE
}

// async global->LDS, 16B per lane; LDS dest is wave-uniform base + lane*16
__device__ __forceinline__ void glds16(const void* g, void* l) {
    __builtin_amdgcn_global_load_lds(
        (const __attribute__((address_space(1))) unsigned int*)g,
        (__attribute__((address_space(3))) unsigned int*)l, 16, 0, 0);
}

#define MFMA16(A, B, C) __builtin_amdgcn_mfma_f32_16x16x32_bf16(A, B, C, 0, 0, 0)

// ---------------------------------------------------------------------------
// v11b — ONE fused kernel (v11 with the fence fix: __threadfence instead of
// the nonexistent __hip_atomic_fence).
// Phase A: prep (transpose/weights/E/halo) as a virtual-block loop;
// device-scope atomic arrive-and-spin barrier (all 768 blocks resident:
// LDS 27.6KB -> 5 blocks/CU capacity >= 3 used); Phase B: conv (v8's verified
// 56.8us body). Motivation: total-minus-conv has been a constant ~93-95us
// across v2-v10 and was never attacked; fusing deletes one launch +
// inter-kernel drain, and fused_dur - 57 finally pins prep's absolute cost.
// Prep transpose write mapping: ci=(i&15)+16*(i>>8), seg=(i>>4)&15 ->
// each LDS write instr = 16 ci x 4 rows -> ~2-way bank conflict (was 8-16-way
// with the 4ci x 16seg mapping; pitch 104: bank = s*16+20j+ci/2 -> 4 banks).
// Barrier is monotonic-counter (memset-zeroed per launch) -> hang-safe even
// if rocprof re-executes the dispatch without the memset.
// ---------------------------------------------------------------------------
__global__ __launch_bounds__(256, 3) void fused_all(
    const float* __restrict__ x,  unsigned short* __restrict__ xTp,
    const float* __restrict__ Wm, unsigned short* __restrict__ Wt,
    const float* __restrict__ extra, const float* __restrict__ Wx,
    const float* __restrict__ bm, const float* __restrict__ bx,
    float* __restrict__ E, float* __restrict__ out,
    unsigned int* __restrict__ bar)
{
    __shared__ __align__(16) unsigned char smem[TAPSZ * 2];   // 27,648 B
    unsigned short (*tile)[CIN + 8] = (unsigned short (*)[CIN + 8])smem; // 13,312 B
    unsigned short *Bs = (unsigned short*)smem;

    const int t = threadIdx.x;

    // ================= Phase A: prep =================
    for (int vb = blockIdx.x; vb < PREPB; vb += NBLK) {
        if (vb < TB) {
            int b   = vb / 49;
            int hw0 = (vb % 49) * 64;
            const float* xb = x + (size_t)b * CIN * HW;
            for (int i = t; i < CIN * 16; i += 256) {
                int ci  = (i & 15) + ((i >> 8) << 4);   // 16 ci x 4 seg per instr
                int seg = (i >> 4) & 15;
                float4 v = *(const float4*)(xb + (size_t)ci * HW + hw0 + seg * 4);
                int hwl = seg * 4;
                tile[hwl + 0][ci] = f2bf(v.x);
                tile[hwl + 1][ci] = f2bf(v.y);
                tile[hwl + 2][ci] = f2bf(v.z);
                tile[hwl + 3][ci] = f2bf(v.w);
            }
            __syncthreads();
            int row = t >> 2, part = t & 3;
            int hw = hw0 + row;
            int h  = hw / W_;
            int w  = hw - h * W_;
            const uint4* s = (const uint4*)&tile[row][part * 24];
            uint4* d = (uint4*)(xTp + ((size_t)((b * W2 + h + 1) * W2 + (w + 1))) * CIN
                                    + part * 24);
            d[0] = s[0]; d[1] = s[1]; d[2] = s[2];
        } else if (vb < TB + WB) {
            int i = (vb - TB) * 256 + t;      // [0, 124416)
            int tap = i / 13824;
            int r1  = i - tap * 13824;
            int g   = r1 / 1152;
            int r2  = r1 - g * 1152;
            int co  = r2 >> 3;
            int e   = r2 & 7;
            int ci  = g * 8 + e;
            Wt[i] = f2bf(Wm[((size_t)co * CIN + ci) * 9 + tap]);
        } else if (vb < TB + WB + EB) {
            int i = (vb - TB - WB) * 256 + t; // [0, 4608)
            int b = i / COUT, co = i - b * COUT;
            float base = bm[co] + bx[co];
            float m[3][3] = {{0,0,0},{0,0,0},{0,0,0}};
            for (int f = 0; f < 3; ++f) {
                float e = extra[(size_t)b * (COUT * 3) + co * 3 + f];
                const float* w = Wx + ((size_t)co * 3 + f) * 9;
                for (int rc = 0; rc < 3; ++rc) {
                    int kh0 = (rc == 0) ? 1 : 0;
                    int kh1 = (rc == 2) ? 1 : 2;
                    for (int cc = 0; cc < 3; ++cc) {
                        int kw0 = (cc == 0) ? 1 : 0;
                        int kw1 = (cc == 2) ? 1 : 2;
                        float s = 0.f;
                        for (int kh = kh0; kh <= kh1; ++kh)
                            for (int kw = kw0; kw <= kw1; ++kw)
                                s += w[kh * 3 + kw];
                        m[rc][cc] += e * s;
                    }
                }
            }
            float* dst = E + (size_t)i * 9;
            for (int rc = 0; rc < 3; ++rc)
                for (int cc = 0; cc < 3; ++cc)
                    dst[rc * 3 + cc] = base + m[rc][cc];
        } else {
            int i = (vb - TB - WB - EB) * 256 + t;   // [0, 87552)
            int b = i / 2736;
            int r = i - b * 2736;
            size_t base_b = (size_t)b * PLANE * CIN;
            size_t addr;
            if (r < 696) {
                addr = base_b + (size_t)r * 8;
            } else if (r < 1392) {
                addr = base_b + (size_t)57 * W2 * CIN + (size_t)(r - 696) * 8;
            } else if (r < 2064) {
                int r2 = r - 1392;
                int h = 1 + r2 / 12, u = r2 - (r2 / 12) * 12;
                addr = base_b + (size_t)(h * W2) * CIN + (size_t)u * 8;
            } else {
                int r2 = r - 2064;
                int h = 1 + r2 / 12, u = r2 - (r2 / 12) * 12;
                addr = base_b + (size_t)(h * W2 + 57) * CIN + (size_t)u * 8;
            }
            *(short8*)(xTp + addr) = (short8){0, 0, 0, 0, 0, 0, 0, 0};
        }
        __syncthreads();   // tile reuse / uniform loop
    }

    // ============== device-wide barrier ==============
    __threadfence();   // release: prep writes visible at agent scope
    if (t == 0) {
        __hip_atomic_fetch_add(bar, 1u, __ATOMIC_ACQ_REL, __HIP_MEMORY_SCOPE_AGENT);
        while (__hip_atomic_load(bar, __ATOMIC_ACQUIRE, __HIP_MEMORY_SCOPE_AGENT) < NBLK)
            __builtin_amdgcn_s_sleep(4);
    }
    __syncthreads();
    __threadfence();   // acquire: see all other blocks' prep writes

    // ================= Phase B: conv (v8 body) =================
    int wv = t >> 6, lane = t & 63;
    int r16 = lane & 15, q = lane >> 4;
    const bool bTail = (t < 192);
    const unsigned short* BpBase = Bs + (q * COUT + r16) * 8;

    for (int cb = blockIdx.x; cb < CONVB; cb += NBLK) {
        int pixBase = cb * MT;

        floatx4 acc[2][9];
        #pragma unroll
        for (int m = 0; m < 2; ++m)
            #pragma unroll
            for (int n = 0; n < 9; ++n)
                acc[m][n] = (floatx4){0.f, 0.f, 0.f, 0.f};

        int aOff[2];
        #pragma unroll
        for (int ms = 0; ms < 2; ++ms) {
            int p = pixBase + wv * 32 + ms * 16 + r16;
            int b = p / HW;
            int hw = p - b * HW;
            int h = hw / W_;
            int w = hw - h * W_;
            aOff[ms] = ((b * W2 + h + 1) * W2 + (w + 1)) * CIN + q * 8;
        }

        short8 a[2][3];
        {
            const unsigned short* bT = xTp - (ptrdiff_t)((W2 + 1) * CIN);
            #pragma unroll
            for (int ms = 0; ms < 2; ++ms)
                #pragma unroll
                for (int ks = 0; ks < 3; ++ks)
                    a[ms][ks] = *(const short8*)(bT + aOff[ms] + ks * 32);
        }

        #pragma unroll 1
        for (int tap = 0; tap < 9; ++tap) {
            const unsigned short* wsrc = Wt + tap * TAPSZ;
            #pragma unroll
            for (int j = 0; j < 6; ++j)
                glds16(wsrc + (t + j * 256) * 8, (void*)(Bs + (t + j * 256) * 8));
            if (bTail)
                glds16(wsrc + (1536 + t) * 8, (void*)(Bs + (1536 + t) * 8));
            __syncthreads();   // B ready

            const int t1 = (tap < 8) ? tap + 1 : 8;
            const int r3 = (t1 * 11) >> 5;
            const unsigned short* bT =
                xTp + (ptrdiff_t)(((r3 - 1) * W2 + (t1 - r3 * 3 - 1)) * CIN);

            #pragma unroll
            for (int ks = 0; ks < 3; ++ks) {
                #pragma unroll
                for (int n3 = 0; n3 < 3; ++n3) {
                    short8 b0 = *(const short8*)(BpBase + ks * 4608 + (n3 * 3 + 0) * 128);
                    short8 b1 = *(const short8*)(BpBase + ks * 4608 + (n3 * 3 + 1) * 128);
                    short8 b2 = *(const short8*)(BpBase + ks * 4608 + (n3 * 3 + 2) * 128);
                    #pragma unroll
                    for (int ms = 0; ms < 2; ++ms)
                        acc[ms][n3 * 3 + 0] = MFMA16(a[ms][ks], b0, acc[ms][n3 * 3 + 0]);
                    #pragma unroll
                    for (int ms = 0; ms < 2; ++ms)
                        acc[ms][n3 * 3 + 1] = MFMA16(a[ms][ks], b1, acc[ms][n3 * 3 + 1]);
                    #pragma unroll
                    for (int ms = 0; ms < 2; ++ms)
                        acc[ms][n3 * 3 + 2] = MFMA16(a[ms][ks], b2, acc[ms][n3 * 3 + 2]);
                }
                #pragma unroll
                for (int ms = 0; ms < 2; ++ms)
                    a[ms][ks] = *(const short8*)(bT + aOff[ms] + ks * 32);
            }
            __syncthreads();   // release Bs for next stage
        }

        #pragma unroll
        for (int ms = 0; ms < 2; ++ms) {
            int p0 = pixBase + wv * 32 + ms * 16 + q * 4;
            int b  = p0 / HW;
            int hw0 = p0 - b * HW;
            int h = hw0 / W_;
            int w0 = hw0 - h * W_;
            int rc = (h == 0) ? 0 : ((h == H_ - 1) ? 2 : 1);
            int cc0 = (w0 == 0) ? 0 : ((w0 == W_ - 1) ? 2 : 1);
            int cc1 = (w0 + 1 == W_ - 1) ? 2 : 1;
            int cc2 = (w0 + 2 == W_ - 1) ? 2 : 1;
            int cc3 = (w0 + 3 == W_ - 1) ? 2 : 1;
            const float* Ebase = E + (size_t)b * COUT * 9 + rc * 3;
            float* outB = out + (size_t)b * COUT * HW + hw0;
            #pragma unroll
            for (int n = 0; n < 9; ++n) {
                int co = n * 16 + r16;
                const float* Eb = Ebase + co * 9;
                float4 v;
                v.x = acc[ms][n][0] + Eb[cc0];
                v.y = acc[ms][n][1] + Eb[cc1];
                v.z = acc[ms][n][2] + Eb[cc2];
                v.w = acc[ms][n][3] + Eb[cc3];
                *(float4*)(outB + (size_t)co * HW) = v;
            }
        }
    }
}

// ---------------------------------------------------------------------------
extern "C" void kernel_launch(void* const* d_in, const int* in_sizes, int n_in,
                              void* d_out, int out_size, void* d_ws, size_t ws_size,
                              hipStream_t stream) {
    const float* x     = (const float*)d_in[0];
    const float* extra = (const float*)d_in[1];
    const float* Wm    = (const float*)d_in[2];
    const float* bm    = (const float*)d_in[3];
    const float* Wx    = (const float*)d_in[4];
    const float* bx    = (const float*)d_in[5];
    float* out = (float*)d_out;

    const size_t XT_BYTES = XTP_SHORTS * 2;            // 20,668,416
    const size_t WT_BYTES = (size_t)COUT * KTOT * 2;   //    248,832
    const size_t E_BYTES  = (size_t)B_ * COUT * 9 * 4; //    165,888
    const size_t BAR_OFF  = XT_BYTES + WT_BYTES + E_BYTES;
    if (ws_size < BAR_OFF + 64) return;

    unsigned short* xTp = (unsigned short*)d_ws;
    unsigned short* Wt  = (unsigned short*)((char*)d_ws + XT_BYTES);
    float*          E   = (float*)((char*)d_ws + XT_BYTES + WT_BYTES);
    unsigned int*   bar = (unsigned int*)((char*)d_ws + BAR_OFF);

    (void)hipMemsetAsync(bar, 0, 64, stream);   // stream-ordered, graph-capture-safe
    fused_all<<<NBLK, 256, 0, stream>>>(x, xTp, Wm, Wt, extra, Wx, bm, bx, E, out, bar);
}